// Round 14
// baseline (194.205 us; speedup 1.0000x reference)
//
#include <hip/hip_runtime.h>
#include <hip/hip_fp16.h>

#define N_NODES_C 50000
#define N_EDGES_C 800000
#define K_FEAT 128
#define HM_STRIDE 256  // [h(128) | mean(128)] fp16 per node
#define NB_C 196       // coarse buckets / edge blocks (196*4096 >= 800000; 50000 <= 196*256)
#define MEAN_NB (N_NODES_C / 4)  // 12500 node-blocks per pass

typedef unsigned int uint_t;
typedef signed char schar;
typedef schar schar8 __attribute__((ext_vector_type(8)));
typedef _Float16 half8 __attribute__((ext_vector_type(8)));
typedef _Float16 half4 __attribute__((ext_vector_type(4)));
typedef float f32x4 __attribute__((ext_vector_type(4)));

// int8 gather rows live in 2 column-slices: q[p][node][64], p=0,1 (cols p*64..p*64+63).
// Each slice = 3.2MB <= 4MiB per-XCD L2 -> the mean pass gather is L2-resident.

// ================= CSR build via 2-level bucket sort (NO global atomics) =================

__global__ __launch_bounds__(256) void p1hist_conv_kernel(
    const int* __restrict__ dst, uint_t* __restrict__ histG, int E,
    const float* __restrict__ feat, _Float16* __restrict__ hm0,
    schar* __restrict__ q0, float* __restrict__ sc0,
    const float* __restrict__ Ws0, const float* __restrict__ Wn0,
    const float* __restrict__ Ws1, const float* __restrict__ Wn1,
    const float* __restrict__ Ws2, const float* __restrict__ Wn2,
    _Float16* __restrict__ WT0, _Float16* __restrict__ WT1, _Float16* __restrict__ WT2) {
    const int t = threadIdx.x, b = blockIdx.x;
    if (b < NB_C) {
        __shared__ uint_t hist[256];
        hist[t] = 0;
        __syncthreads();
        const int base = b * 4096;
#pragma unroll
        for (int j = 0; j < 16; ++j) {
            int idx = base + t + j * 256;
            if (idx < E) atomicAdd(&hist[((uint_t)dst[idx]) >> 8], 1u);
        }
        __syncthreads();
        histG[b * 256 + t] = hist[t];
    } else {
        const int i = (b - NB_C) * 256 + t;
        const int n4 = N_NODES_C * K_FEAT / 4;  // 1,600,000 float4s (32 threads per row)
        if (i < n4) {
            float4 v = reinterpret_cast<const float4*>(feat)[i];
            int n = i >> 5, c4 = i & 31;  // c4 == t&31
            half4 o;
            o.x = (_Float16)v.x; o.y = (_Float16)v.y; o.z = (_Float16)v.z; o.w = (_Float16)v.w;
            *reinterpret_cast<half4*>(hm0 + (size_t)n * HM_STRIDE + c4 * 4) = o;
            float m = fmaxf(fmaxf(fabsf(v.x), fabsf(v.y)), fmaxf(fabsf(v.z), fabsf(v.w)));
            m = fmaxf(m, __shfl_xor(m, 1, 64));
            m = fmaxf(m, __shfl_xor(m, 2, 64));
            m = fmaxf(m, __shfl_xor(m, 4, 64));
            m = fmaxf(m, __shfl_xor(m, 8, 64));
            m = fmaxf(m, __shfl_xor(m, 16, 64));
            const float inv = (m > 0.f) ? 127.0f / m : 0.f;
            uint_t w = ((uint_t)(unsigned char)(schar)rintf(v.x * inv)) |
                       ((uint_t)(unsigned char)(schar)rintf(v.y * inv) << 8) |
                       ((uint_t)(unsigned char)(schar)rintf(v.z * inv) << 16) |
                       ((uint_t)(unsigned char)(schar)rintf(v.w * inv) << 24);
            const int p = c4 >> 4, wc = (c4 & 15) * 4;  // slice, within-slice byte offset
            *reinterpret_cast<uint_t*>(q0 + ((size_t)p * N_NODES_C + n) * 64 + wc) = w;
            if ((t & 31) == 0) sc0[n] = m * (1.0f / 127.0f);
        } else {
            int idx = i - n4;
            if (idx >= 81920) return;
            const float* Ws;
            const float* Wn;
            _Float16* WT;
            int ncol;
            if (idx < 32768) { Ws = Ws0; Wn = Wn0; WT = WT0; ncol = 128; }
            else if (idx < 65536) { idx -= 32768; Ws = Ws1; Wn = Wn1; WT = WT1; ncol = 128; }
            else { idx -= 65536; Ws = Ws2; Wn = Wn2; WT = WT2; ncol = 64; }
            int k = idx & 255, c = idx >> 8;
            float v = (k < 128) ? Ws[(size_t)k * ncol + c] : Wn[(size_t)(k - 128) * ncol + c];
            WT[(size_t)c * 256 + k] = (_Float16)v;
        }
    }
}

__global__ __launch_bounds__(256) void p1scan_kernel(uint_t* __restrict__ histG,
                                                     uint_t* __restrict__ cbase) {
    const int t = threadIdx.x;
    uint_t run = 0;
    for (int bb = 0; bb < NB_C; bb += 28) {
        uint_t vals[28];
#pragma unroll
        for (int j = 0; j < 28; ++j) vals[j] = histG[(size_t)(bb + j) * 256 + t];
#pragma unroll
        for (int j = 0; j < 28; ++j) {
            uint_t x = vals[j];
            vals[j] = run;
            run += x;
        }
#pragma unroll
        for (int j = 0; j < 28; ++j) histG[(size_t)(bb + j) * 256 + t] = vals[j];
    }
    const int lane = t & 63, wid = t >> 6;
    uint_t x = run;
#pragma unroll
    for (int off = 1; off < 64; off <<= 1) {
        uint_t y = __shfl_up(x, off, 64);
        if (lane >= off) x += y;
    }
    __shared__ uint_t wsum[4];
    if (lane == 63) wsum[wid] = x;
    __syncthreads();
    uint_t wpre = 0;
#pragma unroll
    for (int w = 0; w < 4; ++w)
        if (w < wid) wpre += wsum[w];
    uint_t incl = wpre + x;
    cbase[t] = incl - run;
    if (t == 255) cbase[256] = incl;  // == E
}

__global__ __launch_bounds__(256) void p1scatter_kernel(const int* __restrict__ src,
                                                        const int* __restrict__ dst,
                                                        const uint_t* __restrict__ histG,
                                                        const uint_t* __restrict__ cbase,
                                                        uint_t* __restrict__ tmp, int E) {
    __shared__ uint_t cur[256];
    const int t = threadIdx.x, b = blockIdx.x;
    cur[t] = histG[b * 256 + t] + cbase[t];
    __syncthreads();
    const int base = b * 4096;
#pragma unroll
    for (int j = 0; j < 16; ++j) {
        int idx = base + t + j * 256;
        if (idx < E) {
            uint_t d = (uint_t)dst[idx];
            uint_t s = (uint_t)src[idx];  // < 50000 < 2^16
            uint_t slot = atomicAdd(&cur[d >> 8], 1u);
            tmp[slot] = ((d & 255u) << 16) | s;
        }
    }
}

__global__ __launch_bounds__(256) void p2_kernel(const uint_t* __restrict__ tmp,
                                                 const uint_t* __restrict__ cbase,
                                                 int* __restrict__ offs, int* __restrict__ ssrc) {
    __shared__ uint_t hist[256];
    __shared__ uint_t cur[256];
    __shared__ uint_t wsum[4];
    const int t = threadIdx.x, c = blockIdx.x;
    const uint_t cb = cbase[c], ce = cbase[c + 1];
    hist[t] = 0;
    __syncthreads();
    for (uint_t i = cb + t; i < ce; i += 256) atomicAdd(&hist[tmp[i] >> 16], 1u);
    __syncthreads();
    const uint_t v = hist[t];
    const int lane = t & 63, wid = t >> 6;
    uint_t x = v;
#pragma unroll
    for (int off = 1; off < 64; off <<= 1) {
        uint_t y = __shfl_up(x, off, 64);
        if (lane >= off) x += y;
    }
    if (lane == 63) wsum[wid] = x;
    __syncthreads();
    uint_t wpre = 0;
#pragma unroll
    for (int w = 0; w < 4; ++w)
        if (w < wid) wpre += wsum[w];
    const uint_t excl = wpre + x - v;
    const int node = c * 256 + t;
    if (node < N_NODES_C) offs[node] = (int)(cb + excl);
    if (c == 0 && t == 0) offs[N_NODES_C] = N_EDGES_C;
    cur[t] = excl;
    __syncthreads();
    for (uint_t i = cb + t; i < ce; i += 256) {
        uint_t p = tmp[i];
        uint_t slot = cb + atomicAdd(&cur[p >> 16], 1u);
        ssrc[slot] = (int)(p & 0xFFFFu);
    }
}

// ================= mean: 2 passes over int8 column slices (L2-resident) =================
// Pass p gathers slice q[p] (3.2MB). 64B row = 8 lanes x 8B -> one wave-load = 8 edges.
// g=lane>>3 -> edge e+g; c=lane&7 -> cols c*8..c*8+7 of the slice.
// Per-row scale folded into fma. Cross-group combine: shfl_xor 8/16/32.

__global__ __launch_bounds__(256) void mean_pass_kernel(const schar* __restrict__ q,
                                                        const float* __restrict__ qsc,
                                                        _Float16* __restrict__ hm,
                                                        const int* __restrict__ offs,
                                                        const int* __restrict__ ssrc) {
    const int blk = blockIdx.x;
    const int pass = blk / MEAN_NB;
    const int nb = blk - pass * MEAN_NB;
    const int node = nb * 4 + (threadIdx.x >> 6);
    const int lane = threadIdx.x & 63;
    const int g = lane >> 3;
    const int cb = (lane & 7) * 8;
    const schar* base = q + (size_t)pass * N_NODES_C * 64 + cb;
    const int beg = offs[node], end = offs[node + 1];

    float accA[8] = {0.f, 0.f, 0.f, 0.f, 0.f, 0.f, 0.f, 0.f};
    float accB[8] = {0.f, 0.f, 0.f, 0.f, 0.f, 0.f, 0.f, 0.f};

    int e = beg;
    for (; e + 16 <= end; e += 16) {
        const int s0 = ssrc[e + g];
        const int s1 = ssrc[e + 8 + g];
        const float c0 = qsc[s0], c1 = qsc[s1];
        schar8 v0 = *reinterpret_cast<const schar8*>(base + (size_t)s0 * 64);
        schar8 v1 = *reinterpret_cast<const schar8*>(base + (size_t)s1 * 64);
#pragma unroll
        for (int j = 0; j < 8; ++j) accA[j] += c0 * (float)v0[j];
#pragma unroll
        for (int j = 0; j < 8; ++j) accB[j] += c1 * (float)v1[j];
    }
    for (; e + 8 <= end; e += 8) {
        const int s0 = ssrc[e + g];
        const float c0 = qsc[s0];
        schar8 v0 = *reinterpret_cast<const schar8*>(base + (size_t)s0 * 64);
#pragma unroll
        for (int j = 0; j < 8; ++j) accA[j] += c0 * (float)v0[j];
    }
    if (e < end) {
        const bool valid = (e + g) < end;
        const int s0 = valid ? ssrc[e + g] : ssrc[beg];
        const float c0 = valid ? qsc[s0] : 0.f;
        schar8 v0 = *reinterpret_cast<const schar8*>(base + (size_t)s0 * 64);
#pragma unroll
        for (int j = 0; j < 8; ++j) accB[j] += c0 * (float)v0[j];
    }

    const float inv = (end > beg) ? 1.0f / (float)(end - beg) : 0.f;
    half8 o;
#pragma unroll
    for (int j = 0; j < 8; ++j) {
        float x = accA[j] + accB[j];
        x += __shfl_xor(x, 8, 64);
        x += __shfl_xor(x, 16, 64);
        x += __shfl_xor(x, 32, 64);
        o[j] = (_Float16)(x * inv);
    }
    if (lane < 8)
        *reinterpret_cast<half8*>(hm + (size_t)node * HM_STRIDE + 128 + pass * 64 + cb) = o;
}

// ================= MFMA GEMM: out = act(hm @ Wcat + b), K=256 =================
// As R13; epilogue q-stores re-indexed into the [2][N][64] slice layout.

template <int NCOL, bool ACT, bool OUT_FP32>
__global__ __launch_bounds__(256) void sage_mfma(
    const _Float16* __restrict__ hm,  // [n][256]
    const _Float16* __restrict__ WT,  // [NCOL][256]
    const float* __restrict__ bias,
    float* __restrict__ outf,         // OUT_FP32: [n][NCOL]
    _Float16* __restrict__ outh,      // else: next hm h-part
    schar* __restrict__ qout,         // else: next int8 slices [2][N][64]
    float* __restrict__ scout,        // else: next per-row scales
    int nNodes) {
    constexpr int CF = NCOL / 16;
    constexpr int RPB = 128;

    __shared__ _Float16 bl[NCOL][256];

    const int t = threadIdx.x;
#pragma unroll
    for (int it = 0; it < NCOL * 32 / 256; ++it) {
        int f = t + it * 256;
        int row = f >> 5, c8 = f & 31;
        half8 v = *reinterpret_cast<const half8*>(WT + (size_t)row * 256 + c8 * 8);
        int col = (c8 * 8) ^ ((row & 7) << 3);
        *reinterpret_cast<half8*>(&bl[row][col]) = v;
    }
    __syncthreads();

    const int wid = t >> 6;
    const int lane = t & 63;
    const int r0 = blockIdx.x * RPB + wid * 32;
    const int koff = (lane >> 4) * 8;

    half8 a[2][8];
#pragma unroll
    for (int fr = 0; fr < 2; ++fr) {
        int row = r0 + fr * 16 + (lane & 15);
        if (row >= nNodes) row = nNodes - 1;
        const _Float16* ap = hm + (size_t)row * HM_STRIDE + koff;
#pragma unroll
        for (int ks = 0; ks < 8; ++ks)
            a[fr][ks] = *reinterpret_cast<const half8*>(ap + ks * 32);
    }

    f32x4 acc[2][CF];
#pragma unroll
    for (int fr = 0; fr < 2; ++fr)
#pragma unroll
        for (int c = 0; c < CF; ++c) acc[fr][c] = {0.f, 0.f, 0.f, 0.f};

#pragma unroll
    for (int c = 0; c < CF; ++c) {
        const int brow = c * 16 + (lane & 15);
        const int bswz = (brow & 7) << 3;
#pragma unroll
        for (int ks = 0; ks < 8; ++ks) {
            half8 b = *reinterpret_cast<const half8*>(&bl[brow][(ks * 32 + koff) ^ bswz]);
            acc[0][c] = __builtin_amdgcn_mfma_f32_16x16x32_f16(a[0][ks], b, acc[0][c], 0, 0, 0);
            acc[1][c] = __builtin_amdgcn_mfma_f32_16x16x32_f16(a[1][ks], b, acc[1][c], 0, 0, 0);
        }
    }

    const int ocol = lane & 15;
    const int orow_off = (lane >> 4) << 2;
    float bv[CF];
#pragma unroll
    for (int c = 0; c < CF; ++c) bv[c] = bias[c * 16 + ocol];

#pragma unroll
    for (int fr = 0; fr < 2; ++fr) {
#pragma unroll
        for (int reg = 0; reg < 4; ++reg) {
            const int row = r0 + fr * 16 + orow_off + reg;  // uniform across the 16 ocol lanes
            float vals[CF];
            float m = 0.f;
#pragma unroll
            for (int c = 0; c < CF; ++c) {
                float v = acc[fr][c][reg] + bv[c];
                if (ACT) v = fmaxf(v, 0.f);
                vals[c] = v;
                m = fmaxf(m, fabsf(v));
            }
            if (OUT_FP32) {
                if (row < nNodes) {
#pragma unroll
                    for (int c = 0; c < CF; ++c)
                        outf[(size_t)row * NCOL + c * 16 + ocol] = vals[c];
                }
            } else {
                m = fmaxf(m, __shfl_xor(m, 1, 64));
                m = fmaxf(m, __shfl_xor(m, 2, 64));
                m = fmaxf(m, __shfl_xor(m, 4, 64));
                m = fmaxf(m, __shfl_xor(m, 8, 64));
                const float qinv = (m > 0.f) ? 127.0f / m : 0.f;
                if (row < nNodes) {
#pragma unroll
                    for (int c = 0; c < CF; ++c) {
                        const int col = c * 16 + ocol;
                        outh[(size_t)row * HM_STRIDE + col] = (_Float16)vals[c];
                        qout[((size_t)(col >> 6) * N_NODES_C + row) * 64 + (col & 63)] =
                            (schar)rintf(vals[c] * qinv);
                    }
                    if (ocol == 0) scout[row] = m * (1.0f / 127.0f);
                }
            }
        }
    }
}

// ================= launch =================

extern "C" void kernel_launch(void* const* d_in, const int* in_sizes, int n_in,
                              void* d_out, int out_size, void* d_ws, size_t ws_size,
                              hipStream_t stream) {
    const float* feat = (const float*)d_in[0];
    const int* src = (const int*)d_in[1];
    const int* dst = (const int*)d_in[2];
    const float* Ws0 = (const float*)d_in[3];
    const float* Wn0 = (const float*)d_in[4];
    const float* b0 = (const float*)d_in[5];
    const float* Ws1 = (const float*)d_in[6];
    const float* Wn1 = (const float*)d_in[7];
    const float* b1 = (const float*)d_in[8];
    const float* Ws2 = (const float*)d_in[9];
    const float* Wn2 = (const float*)d_in[10];
    const float* b2 = (const float*)d_in[11];
    float* out = (float*)d_out;

    auto align_up = [](size_t x) { return (x + 255) & ~(size_t)255; };
    char* w = (char*)d_ws;
    uint_t* histG = (uint_t*)w; w += align_up((size_t)NB_C * 256 * 4);
    uint_t* cbase = (uint_t*)w; w += align_up(257 * 4);
    uint_t* tmp = (uint_t*)w;   w += align_up((size_t)N_EDGES_C * 4);
    int* offs = (int*)w;        w += align_up((size_t)(N_NODES_C + 1) * 4);
    int* ssrc = (int*)w;        w += align_up((size_t)N_EDGES_C * 4);
    _Float16* hm0 = (_Float16*)w; w += align_up((size_t)N_NODES_C * HM_STRIDE * 2);
    _Float16* hm1 = (_Float16*)w; w += align_up((size_t)N_NODES_C * HM_STRIDE * 2);
    schar* q0 = (schar*)w;      w += align_up((size_t)N_NODES_C * 128);
    schar* q1 = (schar*)w;      w += align_up((size_t)N_NODES_C * 128);
    float* sc0 = (float*)w;     w += align_up((size_t)N_NODES_C * 4);
    float* sc1 = (float*)w;     w += align_up((size_t)N_NODES_C * 4);
    _Float16* WT0 = (_Float16*)w; w += align_up((size_t)128 * 256 * 2);
    _Float16* WT1 = (_Float16*)w; w += align_up((size_t)128 * 256 * 2);
    _Float16* WT2 = (_Float16*)w; w += align_up((size_t)64 * 256 * 2);
    _Float16* hm2 = hm0;  // hm0 dead after GEMM0 reads it
    schar* q2 = q0;       // q0 dead after mean0
    float* sc2 = sc0;

    // ---- CSR build + converts ----
    const int convBlocks = (N_NODES_C * K_FEAT / 4 + 81920 + 255) / 256;  // 6570
    p1hist_conv_kernel<<<NB_C + convBlocks, 256, 0, stream>>>(
        dst, histG, N_EDGES_C, feat, hm0, q0, sc0,
        Ws0, Wn0, Ws1, Wn1, Ws2, Wn2, WT0, WT1, WT2);
    p1scan_kernel<<<1, 256, 0, stream>>>(histG, cbase);
    p1scatter_kernel<<<NB_C, 256, 0, stream>>>(src, dst, histG, cbase, tmp, N_EDGES_C);
    p2_kernel<<<NB_C, 256, 0, stream>>>(tmp, cbase, offs, ssrc);

    const int meanBlocks = MEAN_NB * 2;  // 2 passes x 12500 node-blocks
    const int gemmBlocks = (N_NODES_C + 127) / 128;  // 391

    // ---- layer 0 ----
    mean_pass_kernel<<<meanBlocks, 256, 0, stream>>>(q0, sc0, hm0, offs, ssrc);
    sage_mfma<128, true, false><<<gemmBlocks, 256, 0, stream>>>(
        hm0, WT0, b0, nullptr, hm1, q1, sc1, N_NODES_C);

    // ---- layer 1 ----
    mean_pass_kernel<<<meanBlocks, 256, 0, stream>>>(q1, sc1, hm1, offs, ssrc);
    sage_mfma<128, true, false><<<gemmBlocks, 256, 0, stream>>>(
        hm1, WT1, b1, nullptr, hm2, q2, sc2, N_NODES_C);

    // ---- layer 2 ----
    mean_pass_kernel<<<meanBlocks, 256, 0, stream>>>(q2, sc2, hm2, offs, ssrc);
    sage_mfma<64, false, true><<<gemmBlocks, 256, 0, stream>>>(
        hm2, WT2, b2, out, nullptr, nullptr, nullptr, N_NODES_C);
}

// Round 15
// 153.824 us; speedup vs baseline: 1.2625x; 1.2625x over previous
//
#include <hip/hip_runtime.h>
#include <hip/hip_fp16.h>

#define N_NODES_C 50000
#define N_EDGES_C 800000
#define K_FEAT 128
#define HM_STRIDE 256  // [h(128) | mean(128)] fp16 per node
#define NB_C 196       // coarse buckets / edge blocks (196*4096 >= 800000; 50000 <= 196*256)

typedef unsigned int uint_t;
typedef unsigned char uchar;
typedef _Float16 half8 __attribute__((ext_vector_type(8)));
typedef _Float16 half4 __attribute__((ext_vector_type(4)));
typedef float f32x4 __attribute__((ext_vector_type(4)));

// Gather path: biased-uint8 rows q[node][128] (value = (u-128)*scale), per-row scale.
// (float)((w>>8k)&255) compiles to v_cvt_f32_ubyteN -> 2 VALU/value dequant; the
// -128*scale bias is hoisted out of the inner loop via sumc accumulation.

// ================= CSR build via 2-level bucket sort (NO global atomics) =================

__global__ __launch_bounds__(256) void p1hist_conv_kernel(
    const int* __restrict__ dst, uint_t* __restrict__ histG, int E,
    const float* __restrict__ feat, _Float16* __restrict__ hm0,
    uchar* __restrict__ q0, float* __restrict__ sc0,
    const float* __restrict__ Ws0, const float* __restrict__ Wn0,
    const float* __restrict__ Ws1, const float* __restrict__ Wn1,
    const float* __restrict__ Ws2, const float* __restrict__ Wn2,
    _Float16* __restrict__ WT0, _Float16* __restrict__ WT1, _Float16* __restrict__ WT2) {
    const int t = threadIdx.x, b = blockIdx.x;
    if (b < NB_C) {
        __shared__ uint_t hist[256];
        hist[t] = 0;
        __syncthreads();
        const int base = b * 4096;
#pragma unroll
        for (int j = 0; j < 16; ++j) {
            int idx = base + t + j * 256;
            if (idx < E) atomicAdd(&hist[((uint_t)dst[idx]) >> 8], 1u);
        }
        __syncthreads();
        histG[b * 256 + t] = hist[t];
    } else {
        const int i = (b - NB_C) * 256 + t;
        const int n4 = N_NODES_C * K_FEAT / 4;  // 1,600,000 float4s (32 threads per row)
        if (i < n4) {
            float4 v = reinterpret_cast<const float4*>(feat)[i];
            int n = i >> 5, c4 = i & 31;  // c4 == t&31
            half4 o;
            o.x = (_Float16)v.x; o.y = (_Float16)v.y; o.z = (_Float16)v.z; o.w = (_Float16)v.w;
            *reinterpret_cast<half4*>(hm0 + (size_t)n * HM_STRIDE + c4 * 4) = o;
            float m = fmaxf(fmaxf(fabsf(v.x), fabsf(v.y)), fmaxf(fabsf(v.z), fabsf(v.w)));
            m = fmaxf(m, __shfl_xor(m, 1, 64));
            m = fmaxf(m, __shfl_xor(m, 2, 64));
            m = fmaxf(m, __shfl_xor(m, 4, 64));
            m = fmaxf(m, __shfl_xor(m, 8, 64));
            m = fmaxf(m, __shfl_xor(m, 16, 64));
            const float inv = (m > 0.f) ? 127.0f / m : 0.f;
            uint_t b0 = (uint_t)((int)rintf(v.x * inv) + 128) & 255u;
            uint_t b1 = (uint_t)((int)rintf(v.y * inv) + 128) & 255u;
            uint_t b2 = (uint_t)((int)rintf(v.z * inv) + 128) & 255u;
            uint_t b3 = (uint_t)((int)rintf(v.w * inv) + 128) & 255u;
            *reinterpret_cast<uint_t*>(q0 + (size_t)n * 128 + c4 * 4) =
                b0 | (b1 << 8) | (b2 << 16) | (b3 << 24);
            if ((t & 31) == 0) sc0[n] = m * (1.0f / 127.0f);
        } else {
            int idx = i - n4;
            if (idx >= 81920) return;
            const float* Ws;
            const float* Wn;
            _Float16* WT;
            int ncol;
            if (idx < 32768) { Ws = Ws0; Wn = Wn0; WT = WT0; ncol = 128; }
            else if (idx < 65536) { idx -= 32768; Ws = Ws1; Wn = Wn1; WT = WT1; ncol = 128; }
            else { idx -= 65536; Ws = Ws2; Wn = Wn2; WT = WT2; ncol = 64; }
            int k = idx & 255, c = idx >> 8;
            float v = (k < 128) ? Ws[(size_t)k * ncol + c] : Wn[(size_t)(k - 128) * ncol + c];
            WT[(size_t)c * 256 + k] = (_Float16)v;
        }
    }
}

__global__ __launch_bounds__(256) void p1scan_kernel(uint_t* __restrict__ histG,
                                                     uint_t* __restrict__ cbase) {
    const int t = threadIdx.x;
    uint_t run = 0;
    for (int bb = 0; bb < NB_C; bb += 28) {
        uint_t vals[28];
#pragma unroll
        for (int j = 0; j < 28; ++j) vals[j] = histG[(size_t)(bb + j) * 256 + t];
#pragma unroll
        for (int j = 0; j < 28; ++j) {
            uint_t x = vals[j];
            vals[j] = run;
            run += x;
        }
#pragma unroll
        for (int j = 0; j < 28; ++j) histG[(size_t)(bb + j) * 256 + t] = vals[j];
    }
    const int lane = t & 63, wid = t >> 6;
    uint_t x = run;
#pragma unroll
    for (int off = 1; off < 64; off <<= 1) {
        uint_t y = __shfl_up(x, off, 64);
        if (lane >= off) x += y;
    }
    __shared__ uint_t wsum[4];
    if (lane == 63) wsum[wid] = x;
    __syncthreads();
    uint_t wpre = 0;
#pragma unroll
    for (int w = 0; w < 4; ++w)
        if (w < wid) wpre += wsum[w];
    uint_t incl = wpre + x;
    cbase[t] = incl - run;
    if (t == 255) cbase[256] = incl;  // == E
}

__global__ __launch_bounds__(256) void p1scatter_kernel(const int* __restrict__ src,
                                                        const int* __restrict__ dst,
                                                        const uint_t* __restrict__ histG,
                                                        const uint_t* __restrict__ cbase,
                                                        uint_t* __restrict__ tmp, int E) {
    __shared__ uint_t cur[256];
    const int t = threadIdx.x, b = blockIdx.x;
    cur[t] = histG[b * 256 + t] + cbase[t];
    __syncthreads();
    const int base = b * 4096;
#pragma unroll
    for (int j = 0; j < 16; ++j) {
        int idx = base + t + j * 256;
        if (idx < E) {
            uint_t d = (uint_t)dst[idx];
            uint_t s = (uint_t)src[idx];  // < 50000 < 2^16
            uint_t slot = atomicAdd(&cur[d >> 8], 1u);
            tmp[slot] = ((d & 255u) << 16) | s;
        }
    }
}

__global__ __launch_bounds__(256) void p2_kernel(const uint_t* __restrict__ tmp,
                                                 const uint_t* __restrict__ cbase,
                                                 int* __restrict__ offs, int* __restrict__ ssrc) {
    __shared__ uint_t hist[256];
    __shared__ uint_t cur[256];
    __shared__ uint_t wsum[4];
    const int t = threadIdx.x, c = blockIdx.x;
    const uint_t cb = cbase[c], ce = cbase[c + 1];
    hist[t] = 0;
    __syncthreads();
    for (uint_t i = cb + t; i < ce; i += 256) atomicAdd(&hist[tmp[i] >> 16], 1u);
    __syncthreads();
    const uint_t v = hist[t];
    const int lane = t & 63, wid = t >> 6;
    uint_t x = v;
#pragma unroll
    for (int off = 1; off < 64; off <<= 1) {
        uint_t y = __shfl_up(x, off, 64);
        if (lane >= off) x += y;
    }
    if (lane == 63) wsum[wid] = x;
    __syncthreads();
    uint_t wpre = 0;
#pragma unroll
    for (int w = 0; w < 4; ++w)
        if (w < wid) wpre += wsum[w];
    const uint_t excl = wpre + x - v;
    const int node = c * 256 + t;
    if (node < N_NODES_C) offs[node] = (int)(cb + excl);
    if (c == 0 && t == 0) offs[N_NODES_C] = N_EDGES_C;
    cur[t] = excl;
    __syncthreads();
    for (uint_t i = cb + t; i < ce; i += 256) {
        uint_t p = tmp[i];
        uint_t slot = cb + atomicAdd(&cur[p >> 16], 1u);
        ssrc[slot] = (int)(p & 0xFFFFu);
    }
}

// ================= mean: one wave per node, biased-uint8 rows (128B) + per-row scale ====
// 16 lanes cover a row at 8B/lane -> one wave-load = 4 rows. 16 edges in flight.
// Dequant: acc += c_r * cvt_f32_ubyteN(w); bias folded: mean = (acc - 128*sumc)/deg.

static __device__ __forceinline__ void acc8(float* acc, float c, uint2 v) {
    acc[0] += c * (float)(v.x & 255u);
    acc[1] += c * (float)((v.x >> 8) & 255u);
    acc[2] += c * (float)((v.x >> 16) & 255u);
    acc[3] += c * (float)(v.x >> 24);
    acc[4] += c * (float)(v.y & 255u);
    acc[5] += c * (float)((v.y >> 8) & 255u);
    acc[6] += c * (float)((v.y >> 16) & 255u);
    acc[7] += c * (float)(v.y >> 24);
}

__global__ void mean_kernel(const uchar* __restrict__ q, const float* __restrict__ qsc,
                            _Float16* __restrict__ hm, const int* __restrict__ offs,
                            const int* __restrict__ ssrc) {
    const int node = (int)((blockIdx.x * blockDim.x + threadIdx.x) >> 6);
    const int lane = threadIdx.x & 63;
    if (node >= N_NODES_C) return;
    const int beg = offs[node], end = offs[node + 1];
    const int g = lane >> 4;
    const int cb = (lane & 15) * 8;
    const uchar* base = q + cb;

    float accA[8] = {0.f, 0.f, 0.f, 0.f, 0.f, 0.f, 0.f, 0.f};
    float accB[8] = {0.f, 0.f, 0.f, 0.f, 0.f, 0.f, 0.f, 0.f};
    float sumcA = 0.f, sumcB = 0.f;

    int e = beg;
    for (; e + 16 <= end; e += 16) {
        const int s0 = ssrc[e + g];
        const int s1 = ssrc[e + 4 + g];
        const int s2 = ssrc[e + 8 + g];
        const int s3 = ssrc[e + 12 + g];
        const float c0 = qsc[s0], c1 = qsc[s1], c2 = qsc[s2], c3 = qsc[s3];
        uint2 v0 = *reinterpret_cast<const uint2*>(base + (size_t)s0 * 128);
        uint2 v1 = *reinterpret_cast<const uint2*>(base + (size_t)s1 * 128);
        uint2 v2 = *reinterpret_cast<const uint2*>(base + (size_t)s2 * 128);
        uint2 v3 = *reinterpret_cast<const uint2*>(base + (size_t)s3 * 128);
        acc8(accA, c0, v0);
        acc8(accB, c1, v1);
        acc8(accA, c2, v2);
        acc8(accB, c3, v3);
        sumcA += c0 + c2;
        sumcB += c1 + c3;
    }
    for (; e + 8 <= end; e += 8) {
        const int s0 = ssrc[e + g];
        const int s1 = ssrc[e + 4 + g];
        const float c0 = qsc[s0], c1 = qsc[s1];
        uint2 v0 = *reinterpret_cast<const uint2*>(base + (size_t)s0 * 128);
        uint2 v1 = *reinterpret_cast<const uint2*>(base + (size_t)s1 * 128);
        acc8(accA, c0, v0);
        acc8(accB, c1, v1);
        sumcA += c0;
        sumcB += c1;
    }
    for (; e + 4 <= end; e += 4) {
        const int s0 = ssrc[e + g];
        const float c0 = qsc[s0];
        uint2 v0 = *reinterpret_cast<const uint2*>(base + (size_t)s0 * 128);
        acc8(accA, c0, v0);
        sumcA += c0;
    }
    if (e < end) {
        const bool valid = (e + g) < end;
        const int s0 = valid ? ssrc[e + g] : ssrc[beg];
        const float c0 = valid ? qsc[s0] : 0.f;
        uint2 v0 = *reinterpret_cast<const uint2*>(base + (size_t)s0 * 128);
        acc8(accB, c0, v0);
        sumcB += c0;
    }

    const float inv = (end > beg) ? 1.0f / (float)(end - beg) : 0.f;
    float xs = sumcA + sumcB;
    xs += __shfl_xor(xs, 16, 64);
    xs += __shfl_xor(xs, 32, 64);
    const float bias = 128.0f * xs;
    half8 o;
#pragma unroll
    for (int j = 0; j < 8; ++j) {
        float x = accA[j] + accB[j];
        x += __shfl_xor(x, 16, 64);
        x += __shfl_xor(x, 32, 64);
        o[j] = (_Float16)((x - bias) * inv);
    }
    if (lane < 16)
        *reinterpret_cast<half8*>(hm + (size_t)node * HM_STRIDE + 128 + cb) = o;
}

// ================= MFMA GEMM: out = act(hm @ Wcat + b), K=256 =================
// As R13; epilogue emits biased-uint8 q rows + per-row scale.

template <int NCOL, bool ACT, bool OUT_FP32>
__global__ __launch_bounds__(256) void sage_mfma(
    const _Float16* __restrict__ hm,  // [n][256]
    const _Float16* __restrict__ WT,  // [NCOL][256]
    const float* __restrict__ bias,
    float* __restrict__ outf,         // OUT_FP32: [n][NCOL]
    _Float16* __restrict__ outh,      // else: next hm h-part
    uchar* __restrict__ qout,         // else: next biased-uint8 rows
    float* __restrict__ scout,        // else: next per-row scales
    int nNodes) {
    constexpr int CF = NCOL / 16;
    constexpr int RPB = 128;

    __shared__ _Float16 bl[NCOL][256];

    const int t = threadIdx.x;
#pragma unroll
    for (int it = 0; it < NCOL * 32 / 256; ++it) {
        int f = t + it * 256;
        int row = f >> 5, c8 = f & 31;
        half8 v = *reinterpret_cast<const half8*>(WT + (size_t)row * 256 + c8 * 8);
        int col = (c8 * 8) ^ ((row & 7) << 3);
        *reinterpret_cast<half8*>(&bl[row][col]) = v;
    }
    __syncthreads();

    const int wid = t >> 6;
    const int lane = t & 63;
    const int r0 = blockIdx.x * RPB + wid * 32;
    const int koff = (lane >> 4) * 8;

    half8 a[2][8];
#pragma unroll
    for (int fr = 0; fr < 2; ++fr) {
        int row = r0 + fr * 16 + (lane & 15);
        if (row >= nNodes) row = nNodes - 1;
        const _Float16* ap = hm + (size_t)row * HM_STRIDE + koff;
#pragma unroll
        for (int ks = 0; ks < 8; ++ks)
            a[fr][ks] = *reinterpret_cast<const half8*>(ap + ks * 32);
    }

    f32x4 acc[2][CF];
#pragma unroll
    for (int fr = 0; fr < 2; ++fr)
#pragma unroll
        for (int c = 0; c < CF; ++c) acc[fr][c] = {0.f, 0.f, 0.f, 0.f};

#pragma unroll
    for (int c = 0; c < CF; ++c) {
        const int brow = c * 16 + (lane & 15);
        const int bswz = (brow & 7) << 3;
#pragma unroll
        for (int ks = 0; ks < 8; ++ks) {
            half8 b = *reinterpret_cast<const half8*>(&bl[brow][(ks * 32 + koff) ^ bswz]);
            acc[0][c] = __builtin_amdgcn_mfma_f32_16x16x32_f16(a[0][ks], b, acc[0][c], 0, 0, 0);
            acc[1][c] = __builtin_amdgcn_mfma_f32_16x16x32_f16(a[1][ks], b, acc[1][c], 0, 0, 0);
        }
    }

    const int ocol = lane & 15;
    const int orow_off = (lane >> 4) << 2;
    float bv[CF];
#pragma unroll
    for (int c = 0; c < CF; ++c) bv[c] = bias[c * 16 + ocol];

#pragma unroll
    for (int fr = 0; fr < 2; ++fr) {
#pragma unroll
        for (int reg = 0; reg < 4; ++reg) {
            const int row = r0 + fr * 16 + orow_off + reg;  // uniform across the 16 ocol lanes
            float vals[CF];
            float m = 0.f;
#pragma unroll
            for (int c = 0; c < CF; ++c) {
                float v = acc[fr][c][reg] + bv[c];
                if (ACT) v = fmaxf(v, 0.f);
                vals[c] = v;
                m = fmaxf(m, fabsf(v));
            }
            if (OUT_FP32) {
                if (row < nNodes) {
#pragma unroll
                    for (int c = 0; c < CF; ++c)
                        outf[(size_t)row * NCOL + c * 16 + ocol] = vals[c];
                }
            } else {
                m = fmaxf(m, __shfl_xor(m, 1, 64));
                m = fmaxf(m, __shfl_xor(m, 2, 64));
                m = fmaxf(m, __shfl_xor(m, 4, 64));
                m = fmaxf(m, __shfl_xor(m, 8, 64));
                const float qinv = (m > 0.f) ? 127.0f / m : 0.f;
                if (row < nNodes) {
#pragma unroll
                    for (int c = 0; c < CF; ++c) {
                        const int col = c * 16 + ocol;
                        outh[(size_t)row * HM_STRIDE + col] = (_Float16)vals[c];
                        qout[(size_t)row * 128 + col] =
                            (uchar)(((int)rintf(vals[c] * qinv) + 128) & 255);
                    }
                    if (ocol == 0) scout[row] = m * (1.0f / 127.0f);
                }
            }
        }
    }
}

// ================= launch =================

extern "C" void kernel_launch(void* const* d_in, const int* in_sizes, int n_in,
                              void* d_out, int out_size, void* d_ws, size_t ws_size,
                              hipStream_t stream) {
    const float* feat = (const float*)d_in[0];
    const int* src = (const int*)d_in[1];
    const int* dst = (const int*)d_in[2];
    const float* Ws0 = (const float*)d_in[3];
    const float* Wn0 = (const float*)d_in[4];
    const float* b0 = (const float*)d_in[5];
    const float* Ws1 = (const float*)d_in[6];
    const float* Wn1 = (const float*)d_in[7];
    const float* b1 = (const float*)d_in[8];
    const float* Ws2 = (const float*)d_in[9];
    const float* Wn2 = (const float*)d_in[10];
    const float* b2 = (const float*)d_in[11];
    float* out = (float*)d_out;

    auto align_up = [](size_t x) { return (x + 255) & ~(size_t)255; };
    char* w = (char*)d_ws;
    uint_t* histG = (uint_t*)w; w += align_up((size_t)NB_C * 256 * 4);
    uint_t* cbase = (uint_t*)w; w += align_up(257 * 4);
    uint_t* tmp = (uint_t*)w;   w += align_up((size_t)N_EDGES_C * 4);
    int* offs = (int*)w;        w += align_up((size_t)(N_NODES_C + 1) * 4);
    int* ssrc = (int*)w;        w += align_up((size_t)N_EDGES_C * 4);
    _Float16* hm0 = (_Float16*)w; w += align_up((size_t)N_NODES_C * HM_STRIDE * 2);
    _Float16* hm1 = (_Float16*)w; w += align_up((size_t)N_NODES_C * HM_STRIDE * 2);
    uchar* q0 = (uchar*)w;      w += align_up((size_t)N_NODES_C * 128);
    uchar* q1 = (uchar*)w;      w += align_up((size_t)N_NODES_C * 128);
    float* sc0 = (float*)w;     w += align_up((size_t)N_NODES_C * 4);
    float* sc1 = (float*)w;     w += align_up((size_t)N_NODES_C * 4);
    _Float16* WT0 = (_Float16*)w; w += align_up((size_t)128 * 256 * 2);
    _Float16* WT1 = (_Float16*)w; w += align_up((size_t)128 * 256 * 2);
    _Float16* WT2 = (_Float16*)w; w += align_up((size_t)64 * 256 * 2);
    _Float16* hm2 = hm0;  // hm0 dead after GEMM0 reads it
    uchar* q2 = q0;       // q0 dead after mean0
    float* sc2 = sc0;

    // ---- CSR build + converts ----
    const int convBlocks = (N_NODES_C * K_FEAT / 4 + 81920 + 255) / 256;  // 6570
    p1hist_conv_kernel<<<NB_C + convBlocks, 256, 0, stream>>>(
        dst, histG, N_EDGES_C, feat, hm0, q0, sc0,
        Ws0, Wn0, Ws1, Wn1, Ws2, Wn2, WT0, WT1, WT2);
    p1scan_kernel<<<1, 256, 0, stream>>>(histG, cbase);
    p1scatter_kernel<<<NB_C, 256, 0, stream>>>(src, dst, histG, cbase, tmp, N_EDGES_C);
    p2_kernel<<<NB_C, 256, 0, stream>>>(tmp, cbase, offs, ssrc);

    const int meanBlocks = (N_NODES_C * 64 + 255) / 256;
    const int gemmBlocks = (N_NODES_C + 127) / 128;  // 391

    // ---- layer 0 ----
    mean_kernel<<<meanBlocks, 256, 0, stream>>>(q0, sc0, hm0, offs, ssrc);
    sage_mfma<128, true, false><<<gemmBlocks, 256, 0, stream>>>(
        hm0, WT0, b0, nullptr, hm1, q1, sc1, N_NODES_C);

    // ---- layer 1 ----
    mean_kernel<<<meanBlocks, 256, 0, stream>>>(q1, sc1, hm1, offs, ssrc);
    sage_mfma<128, true, false><<<gemmBlocks, 256, 0, stream>>>(
        hm1, WT1, b1, nullptr, hm2, q2, sc2, N_NODES_C);

    // ---- layer 2 ----
    mean_kernel<<<meanBlocks, 256, 0, stream>>>(q2, sc2, hm2, offs, ssrc);
    sage_mfma<64, false, true><<<gemmBlocks, 256, 0, stream>>>(
        hm2, WT2, b2, out, nullptr, nullptr, nullptr, N_NODES_C);
}